// Round 8
// baseline (384.230 us; speedup 1.0000x reference)
//
#include <hip/hip_runtime.h>
#include <math.h>

#define B_ROWS 65536
#define WDIM 512
#define HDIM 8
#define THREADS 512

// Native clang vector type — __builtin_nontemporal_{load,store} require it.
typedef float native_float4 __attribute__((ext_vector_type(4)));

// ---- DPP cross-lane (VALU pipe; avoids ds_swizzle latency/contention) ----
template<int CTRL, int ROWM>
__device__ __forceinline__ float dpp_mov(float oldv, float x) {
    return __int_as_float(__builtin_amdgcn_update_dpp(
        __float_as_int(oldv), __float_as_int(x), CTRL, ROWM, 0xF, false));
}

// Full-wave (64-lane) sum, broadcast via readlane(63). Order bit-exact vs R0.
__device__ __forceinline__ float wave_sum(float x) {
    x += dpp_mov<0x121, 0xF>(0.f, x);   // row_ror:1
    x += dpp_mov<0x122, 0xF>(0.f, x);   // row_ror:2
    x += dpp_mov<0x124, 0xF>(0.f, x);   // row_ror:4
    x += dpp_mov<0x128, 0xF>(0.f, x);   // row_ror:8  -> row-of-16 sums
    x += dpp_mov<0x142, 0xA>(0.f, x);   // row_bcast15
    x += dpp_mov<0x143, 0xC>(0.f, x);   // row_bcast31 -> lane63 = total
    return __int_as_float(__builtin_amdgcn_readlane(__float_as_int(x), 63));
}

__device__ __forceinline__ float wave_max(float x) {
    x = fmaxf(x, dpp_mov<0x121, 0xF>(-INFINITY, x));
    x = fmaxf(x, dpp_mov<0x122, 0xF>(-INFINITY, x));
    x = fmaxf(x, dpp_mov<0x124, 0xF>(-INFINITY, x));
    x = fmaxf(x, dpp_mov<0x128, 0xF>(-INFINITY, x));
    x = fmaxf(x, dpp_mov<0x142, 0xA>(-INFINITY, x));
    x = fmaxf(x, dpp_mov<0x143, 0xC>(-INFINITY, x));
    return __int_as_float(__builtin_amdgcn_readlane(__float_as_int(x), 63));
}

__device__ __forceinline__ float dot8(native_float4 a0, native_float4 a1,
                                      native_float4 b0, native_float4 b1) {
    float s = a0.x * b0.x;
    s = fmaf(a0.y, b0.y, s); s = fmaf(a0.z, b0.z, s); s = fmaf(a0.w, b0.w, s);
    s = fmaf(a1.x, b1.x, s); s = fmaf(a1.y, b1.y, s);
    s = fmaf(a1.z, b1.z, s); s = fmaf(a1.w, b1.w, s);
    return s;
}

// Measured model (R0-R7): occupancy counter ~40-42% for VGPR<=64 classes,
// ~22% for VGPR in (64,128] -> crossing 64 halves resident waves. R7 (2-row,
// VGPR=108, clean): 171us, VALUBusy 45% = 2 waves/SIMD x 23%/wave -> stall-
// bound on serial chains. Compiler cap rule: cap = 256/min_waves_per_EU.
// R5 showed 1-row demand slightly >64 (spilled at cap 64). R8: 1-row +
// prefetch at cap (512,3)=85: est demand 70-78 -> clean, register class
// ~6 waves/SIMD vs R7's ~2-4. Body = R7 row-a path verbatim (e-space radix
// proven absmax 0.0 on HW).
__global__ __launch_bounds__(THREADS, 3)
void fused_mlp_topk(const float* __restrict__ x,
                    const float* __restrict__ W1,
                    const float* __restrict__ b1,
                    const float* __restrict__ W2,
                    const float* __restrict__ b2,
                    const float* __restrict__ W3,
                    const float* __restrict__ b3,
                    float* __restrict__ out)
{
    // W1 as [j][i] (8x512), W3 transposed to [k][i] (8x512): compute reads are
    // 16B/lane stride-16B ds_read_b128 (conflict-free).
    __shared__ __align__(16) float sW1[HDIM * WDIM];
    __shared__ __align__(16) float sW3t[HDIM * WDIM];
    __shared__ __align__(16) float sb3[WDIM];

    const int tid = threadIdx.x;
    for (int i = tid; i < HDIM * WDIM; i += THREADS) sW1[i] = W1[i];
    for (int i = tid; i < HDIM * WDIM; i += THREADS) {
        int r = i >> 3, k = i & 7;          // W3 is (512,8) row-major
        sW3t[k * WDIM + r] = W3[i];
    }
    for (int i = tid; i < WDIM; i += THREADS) sb3[i] = b3[i];
    __syncthreads();

    const int lane = tid & 63;
    const int wave_id = blockIdx.x * (THREADS / 64) + (tid >> 6);   // 8192 waves

    const native_float4* sW1v = reinterpret_cast<const native_float4*>(sW1);
    const native_float4* sW3v = reinterpret_cast<const native_float4*>(sW3t);
    const native_float4* sb3v = reinterpret_cast<const native_float4*>(sb3);

    // Preload first row, non-temporal (read-once stream).
    int ra = wave_id;
    const native_float4* xp = reinterpret_cast<const native_float4*>(x + (size_t)ra * WDIM);
    native_float4 x0 = __builtin_nontemporal_load(xp + lane);
    native_float4 x1 = __builtin_nontemporal_load(xp + lane + 64);

    #pragma unroll 1
    for (int it = 0; it < 8; ++it) {        // 8192 waves * 1 row * 8 = 65536
        // -------- layer 1: 8 dots of 512 --------
        float pa[HDIM];
        #pragma unroll
        for (int j = 0; j < HDIM; ++j) {
            native_float4 w0 = sW1v[j * 128 + lane];
            native_float4 w1 = sW1v[j * 128 + lane + 64];
            pa[j] = dot8(x0, x1, w0, w1);
        }
        float h1[HDIM];
        #pragma unroll
        for (int j = 0; j < HDIM; ++j) {
            float sa = wave_sum(pa[j]) + b1[j];
            h1[j] = sa > 0.f ? sa : 0.f;
        }

        // -------- layer 2: 8x8, wave-uniform --------
        float h2[HDIM];
        #pragma unroll
        for (int j = 0; j < HDIM; ++j) {
            float va = b2[j];
            #pragma unroll
            for (int k = 0; k < HDIM; ++k) {
                const float w = W2[j * HDIM + k];
                va = fmaf(w, h1[k], va);
            }
            h2[j] = va > 0.f ? va : 0.f;
        }

        // -------- layer 3: vector form -> per-element FMA (contracted),
        // packable into v_pk_fma_f32 --------
        native_float4 y0 = sb3v[lane];
        native_float4 y1 = sb3v[lane + 64];
        #pragma unroll
        for (int k = 0; k < HDIM; ++k) {
            const float ha = h2[k];
            native_float4 w0 = sW3v[k * 128 + lane];
            native_float4 w1 = sW3v[k * 128 + lane + 64];
            y0 += ha * w0;  y1 += ha * w1;
        }

        // -------- prefetch next row's x (covered by softmax+radix) -------
        const int nra = ra + 8192;
        native_float4 nx0, nx1;
        if (it < 7) {
            const native_float4* nxp = reinterpret_cast<const native_float4*>(x + (size_t)nra * WDIM);
            nx0 = __builtin_nontemporal_load(nxp + lane);
            nx1 = __builtin_nontemporal_load(nxp + lane + 64);
        }

        // -------- softmax max + exp (e-values bit-identical to R7) --------
        float lma = fmaxf(fmaxf(fmaxf(y0.x, y0.y), fmaxf(y0.z, y0.w)),
                          fmaxf(fmaxf(y1.x, y1.y), fmaxf(y1.z, y1.w)));
        float ma = wave_max(lma);

        float ea[8];
        ea[0] = expf(y0.x - ma); ea[1] = expf(y0.y - ma);
        ea[2] = expf(y0.z - ma); ea[3] = expf(y0.w - ma);
        ea[4] = expf(y1.x - ma); ea[5] = expf(y1.y - ma);
        ea[6] = expf(y1.z - ma); ea[7] = expf(y1.w - ma);

        // e-space top-k (R7-proven, absmax 0.0): p = e/sa monotone in e;
        // forced cols 0/511 are the 2 global maxima -> threshold = 14th
        // largest of the remaining 510. Zero the forced slots for the count.
        if (lane == 0)  ea[0] = 0.f;    // global col 0
        if (lane == 63) ea[7] = 0.f;    // global col 511

        // -------- exact 14th-largest via radix bit-search (e in [2^-31,1]
        // -> bits 30..28 are 011; seed 0x30000000, search 27..0) --------
        unsigned Ua = 0x30000000u;
        for (int b = 27; b >= 0; --b) {
            const unsigned bit = 1u << b;
            const float cfa = __uint_as_float(Ua | bit);
            int ca = 0;
            #pragma unroll
            for (int t = 0; t < 8; ++t)
                ca += __popcll(__ballot(ea[t] > cfa));
            if (ca >= 14) Ua |= bit;
        }
        const float thra = __uint_as_float(Ua + 1u);

        // -------- emit 0/1 mask; forced cols overridden ----------
        native_float4 r0, r1;
        r0.x = ea[0] >= thra ? 1.f : 0.f;  r0.y = ea[1] >= thra ? 1.f : 0.f;
        r0.z = ea[2] >= thra ? 1.f : 0.f;  r0.w = ea[3] >= thra ? 1.f : 0.f;
        r1.x = ea[4] >= thra ? 1.f : 0.f;  r1.y = ea[5] >= thra ? 1.f : 0.f;
        r1.z = ea[6] >= thra ? 1.f : 0.f;  r1.w = ea[7] >= thra ? 1.f : 0.f;
        if (lane == 0)  r0.x = 1.f;
        if (lane == 63) r1.w = 1.f;

        native_float4* oa = reinterpret_cast<native_float4*>(out + (size_t)ra * WDIM);
        __builtin_nontemporal_store(r0, oa + lane);
        __builtin_nontemporal_store(r1, oa + lane + 64);

        ra = nra;
        x0 = nx0; x1 = nx1;
    }
}

extern "C" void kernel_launch(void* const* d_in, const int* in_sizes, int n_in,
                              void* d_out, int out_size, void* d_ws, size_t ws_size,
                              hipStream_t stream) {
    const float* x  = (const float*)d_in[0];
    const float* W1 = (const float*)d_in[1];
    const float* b1 = (const float*)d_in[2];
    const float* W2 = (const float*)d_in[3];
    const float* b2 = (const float*)d_in[4];
    const float* W3 = (const float*)d_in[5];
    const float* b3 = (const float*)d_in[6];
    float* out = (float*)d_out;

    // 1024 blocks x 512 thr = 8192 waves; 1 row/wave/iter x 8 iters = 65536.
    // (512,3): compiler VGPR cap = 256/3 = 85 (measured rule) vs 1-row demand
    // ~70-78 -> clean, and the <=85 register class doubles-ish resident waves
    // vs the 108-VGPR class (measured 22% -> expect ~35-45%).
    fused_mlp_topk<<<dim3(1024), dim3(THREADS), 0, stream>>>(x, W1, b1, W2, b2, W3, b3, out);
}